// Round 11
// baseline (252.699 us; speedup 1.0000x reference)
//
#include <hip/hip_runtime.h>

#define BB 32
#define TT 128
#define II 256
#define HH 256
#define OO 128
#define FWID 512  // H + I

// d_ws: u64 slots[2][BB][HH] (parity, batch, row) = 128 KB.
// Slot = (stamp<<32)|float_bits(h); step s consumes stamp>=s from parity s&1,
// publishes stamp s+1 into parity (s+1)&1. Agent-scope relaxed (no fences);
// protocol proven on HW. Overwrite safety: publish(s+1) only after this
// block's gather(s) => all stamp-(s-1) readers retired. u64 cannot tear.
//
// R23 = R22/R10 (best: kernel 173-183us, harness 220.7) + AGPR WEIGHT STASH:
//  - R22's opacity barrier did NOT pin weights (VGPR stuck at 108 — cannot
//    hold 96 pinned + working set; compiler still streams W/lam/gam from
//    L2/MALL every step = ~6.1MB/step/XCD ≈ the measured 1.4us/step floor).
//  - Fix: stash all 96 weight floats/thread in AGPRs via explicit
//    v_accvgpr_write_b32 ("a" constraint). AGPR values CANNOT be remat'd
//    from memory and fit the unified file: 96 AGPR + ~112 VGPR = 208 <= 256
//    per wave at 2 waves/SIMD (waves_per_eu(2,2), occupancy unchanged).
//    Per-step cost: 96 v_accvgpr_read (full-rate moves, ~192cy/wave) vs
//    removing the L2/MALL streaming floor entirely.
//  - CU register file 512KB; block was using ~220KB; stash uses the idle rest.
// Signature: VGPR_Count ~200+ (arch+acc) or ~112 arch; FETCH/WRITE flat.
// Predicted: BW-floor true -> kernel 120-150us, VALUBusy 55-70%;
// false (flat ~175 w/ signature) -> relay floor confirmed -> near-ceiling.

typedef unsigned long long u64;
typedef float f32x2 __attribute__((ext_vector_type(2)));

__device__ __forceinline__ f32x2 mk2(float a, float b) { f32x2 r; r.x = a; r.y = b; return r; }

__device__ __forceinline__ f32x2 pk_fma(f32x2 a, f32x2 b, f32x2 c) {
    f32x2 d;
    asm("v_pk_fma_f32 %0, %1, %2, %3" : "=v"(d) : "v"(a), "v"(b), "v"(c));
    return d;
}
__device__ __forceinline__ f32x2 pk_mul(f32x2 a, f32x2 b) {
    f32x2 d;
    asm("v_pk_mul_f32 %0, %1, %2" : "=v"(d) : "v"(a), "v"(b));
    return d;
}
__device__ __forceinline__ f32x2 pk_add(f32x2 a, f32x2 b) {
    f32x2 d;
    asm("v_pk_add_f32 %0, %1, %2" : "=v"(d) : "v"(a), "v"(b));
    return d;
}

// ---- AGPR stash: storage the allocator can't stream or remat ----
__device__ __forceinline__ float ag_stash(float v) {
    float r;
    asm volatile("v_accvgpr_write_b32 %0, %1" : "=a"(r) : "v"(v));
    return r;
}
__device__ __forceinline__ float ag_read(float a) {
    float r;
    asm volatile("v_accvgpr_read_b32 %0, %1" : "=v"(r) : "a"(a));
    return r;
}
__device__ __forceinline__ f32x2 ag_read2(float a0, float a1) {
    return mk2(ag_read(a0), ag_read(a1));
}

template<int CTRL>
__device__ __forceinline__ float dpp_add(float x) {
    int t = __builtin_amdgcn_update_dpp(0, __float_as_int(x), CTRL, 0xF, 0xF, true);
    return x + __int_as_float(t);
}
// 16-lane butterfly sum via DPP row_ror; result valid in all 16 lanes.
__device__ __forceinline__ float row16_sum(float x) {
    x = dpp_add<0x128>(x);  // row_ror:8
    x = dpp_add<0x124>(x);  // row_ror:4
    x = dpp_add<0x122>(x);  // row_ror:2
    x = dpp_add<0x121>(x);  // row_ror:1
    return x;
}
// Paired version: interleaves the two dep chains (half the serial latency).
__device__ __forceinline__ void row16_sum2(float& a, float& b) {
    a = dpp_add<0x128>(a); b = dpp_add<0x128>(b);
    a = dpp_add<0x124>(a); b = dpp_add<0x124>(b);
    a = dpp_add<0x122>(a); b = dpp_add<0x122>(b);
    a = dpp_add<0x121>(a); b = dpp_add<0x121>(b);
}

__device__ __forceinline__ u64 slot_ld(const u64* p) {
    return __hip_atomic_load(p, __ATOMIC_RELAXED, __HIP_MEMORY_SCOPE_AGENT);
}

// One wave gathers 256 rows of one batch (4 slots/lane), stages h to LDS
// (ds_write_b128), release-stores an LDS flag. Depth-2 pipelined poll
// (R18-proven variant).
__device__ __forceinline__ void gather_to_lds(const u64* base, int lane, unsigned us,
                                              float* dst, int* flag, int fval) {
    const u64* p = base + 4 * lane;
    u64 a, b, c, d;
    {
        u64 a0 = slot_ld(p), b0 = slot_ld(p + 1), c0 = slot_ld(p + 2), d0 = slot_ld(p + 3);
        for (;;) {
            u64 a1 = slot_ld(p), b1 = slot_ld(p + 1), c1 = slot_ld(p + 2), d1 = slot_ld(p + 3);
            bool ok0 = ((unsigned)(a0 >> 32) >= us) & ((unsigned)(b0 >> 32) >= us) &
                       ((unsigned)(c0 >> 32) >= us) & ((unsigned)(d0 >> 32) >= us);
            if (__all(ok0)) { a = a0; b = b0; c = c0; d = d0; break; }
            a0 = slot_ld(p); b0 = slot_ld(p + 1); c0 = slot_ld(p + 2); d0 = slot_ld(p + 3);
            bool ok1 = ((unsigned)(a1 >> 32) >= us) & ((unsigned)(b1 >> 32) >= us) &
                       ((unsigned)(c1 >> 32) >= us) & ((unsigned)(d1 >> 32) >= us);
            if (__all(ok1)) { a = a1; b = b1; c = c1; d = d1; break; }
        }
    }
    float4 hv;
    hv.x = __uint_as_float((unsigned)a);
    hv.y = __uint_as_float((unsigned)b);
    hv.z = __uint_as_float((unsigned)c);
    hv.w = __uint_as_float((unsigned)d);
    *reinterpret_cast<float4*>(dst + 4 * lane) = hv;
    if (lane == 0)  // release drains the wave's ds_write before the flag
        __hip_atomic_store(flag, fval, __ATOMIC_RELEASE, __HIP_MEMORY_SCOPE_WORKGROUP);
}

__global__ __launch_bounds__(512, 2) __attribute__((amdgpu_waves_per_eu(2, 2)))
void stpn_kernel(const float* __restrict__ x,      // (B,T,I)
                 const float* __restrict__ wlam,   // (H,FWID)
                 const float* __restrict__ wgam,   // (H,FWID)
                 const float* __restrict__ w,      // (H,FWID)
                 const float* __restrict__ bias,   // (H)
                 const float* __restrict__ wout,   // (O,H)
                 const float* __restrict__ bout,   // (O)
                 float* __restrict__ out,          // tag(4096) | h_T(8192) | F_T
                 u64* __restrict__ slots)
{
    __shared__ __align__(16) float lh[2][HH];      // [parity][row]
    __shared__ int lflag[2];                       // [parity]

    const int tid  = threadIdx.x;
    const int bk   = blockIdx.x;
    const int b    = bk & 31;        // batch
    const int sl   = bk >> 5;        // row slice 0..7 (32 rows each)
    const int wv   = tid >> 6;       // 0..7
    const int lane = tid & 63;
    const int g    = tid >> 4;       // 16-lane group 0..31 == row-within-slice
    const int i    = tid & 15;       // lane within group
    const int r    = sl * 32 + (g & 31);

    if (tid < 2) lflag[tid] = 0;

    // Per-lane f-chunks of row r: f = 64*k + 4*i + c. Pair j covers
    // (Wa[2j], Wa[2j+1]); j<8 x-part, j>=8 h-part. All 96 weight floats
    // stashed in AGPRs (one-time ~100cy), F2 stays in VGPRs.
    float Wa[32], La[32], Ga[32];
    f32x2 F2[16];
    {
        const float4* wr = reinterpret_cast<const float4*>(w    + (size_t)r * FWID);
        const float4* lr = reinterpret_cast<const float4*>(wlam + (size_t)r * FWID);
        const float4* gr = reinterpret_cast<const float4*>(wgam + (size_t)r * FWID);
#pragma unroll
        for (int k = 0; k < 8; ++k) {
            float4 t;
            t = wr[k * 16 + i];
            Wa[4*k]   = ag_stash(t.x); Wa[4*k+1] = ag_stash(t.y);
            Wa[4*k+2] = ag_stash(t.z); Wa[4*k+3] = ag_stash(t.w);
            t = lr[k * 16 + i];
            La[4*k]   = ag_stash(t.x); La[4*k+1] = ag_stash(t.y);
            La[4*k+2] = ag_stash(t.z); La[4*k+3] = ag_stash(t.w);
            t = gr[k * 16 + i];
            Ga[4*k]   = ag_stash(t.x); Ga[4*k+1] = ag_stash(t.y);
            Ga[4*k+2] = ag_stash(t.z); Ga[4*k+3] = ag_stash(t.w);
            F2[2*k] = mk2(0.f, 0.f); F2[2*k+1] = mk2(0.f, 0.f);
        }
    }
    const float bj = bias[r];
    float hl = 0.f;

    // preload x(0)
    float4 px0, px1, px2, px3;
    {
        const float4* xb4 = reinterpret_cast<const float4*>(x + (size_t)b * TT * II);
        px0 = xb4[i]; px1 = xb4[16 + i]; px2 = xb4[32 + i]; px3 = xb4[48 + i];
    }

    __syncthreads();   // lflag init visible

    for (int s = 0; s < TT; ++s) {
        const int par = s & 1;

        f32x2 X2[8];
        X2[0] = mk2(px0.x, px0.y); X2[1] = mk2(px0.z, px0.w);
        X2[2] = mk2(px1.x, px1.y); X2[3] = mk2(px1.z, px1.w);
        X2[4] = mk2(px2.x, px2.y); X2[5] = mk2(px2.z, px2.w);
        X2[6] = mk2(px3.x, px3.y); X2[7] = mk2(px3.z, px3.w);

        // ---- Phase P: independent of h(s), runs before the gather ----
        f32x2 tw2[8];                                  // h-part tw, kept for dot_h
        f32x2 dx2 = mk2(0.f, 0.f), nv2 = mk2(0.f, 0.f);
#pragma unroll
        for (int j = 0; j < 8; ++j) {                  // x-part pairs (W from AGPR)
            f32x2 t = pk_add(ag_read2(Wa[2*j], Wa[2*j+1]), F2[j]);
            dx2 = pk_fma(X2[j], t, dx2);
            nv2 = pk_fma(t, t, nv2);
        }
#pragma unroll
        for (int j = 0; j < 8; ++j) {                  // h-part pairs (W from AGPR)
            tw2[j] = pk_add(ag_read2(Wa[16 + 2*j], Wa[16 + 2*j+1]), F2[8 + j]);
            nv2 = pk_fma(tw2[j], tw2[j], nv2);
        }
        float dxs = dx2.x + dx2.y;
        float nrm = nv2.x + nv2.y;
        row16_sum2(dxs, nrm);
        const float invn = __builtin_amdgcn_rsqf(nrm);   // eps 1e-16 negligible, nrm = O(1)
        const f32x2 invn2 = mk2(invn, invn);
        const float dxb = dxs + bj;

        // F decay (h-independent; lambda from AGPR)
#pragma unroll
        for (int j = 0; j < 16; ++j)
            F2[j] = pk_mul(ag_read2(La[2*j], La[2*j+1]), pk_mul(F2[j], invn2));

        // ---- gather (wave 0, pipelined after Phase P; prio-boosted) ----
        if (wv == 0) {
            __builtin_amdgcn_s_setprio(1);
            gather_to_lds(slots + ((size_t)par * BB + b) * HH, lane,
                          (unsigned)s, lh[par], &lflag[par], s + 1);
            __builtin_amdgcn_s_setprio(0);
        }

        // ---- Phase W: LDS flag spin (sleep frees SIMD issue), consume h ----
        while (__hip_atomic_load(&lflag[par], __ATOMIC_ACQUIRE, __HIP_MEMORY_SCOPE_WORKGROUP) <= s) {
            __builtin_amdgcn_s_sleep(1);
        }
        const float4* lh4 = reinterpret_cast<const float4*>(lh[par]);
        float4 ha = lh4[i], hb = lh4[16 + i], hc = lh4[32 + i], hd = lh4[48 + i];
        f32x2 H2[8];
        H2[0] = mk2(ha.x, ha.y); H2[1] = mk2(ha.z, ha.w);
        H2[2] = mk2(hb.x, hb.y); H2[3] = mk2(hb.z, hb.w);
        H2[4] = mk2(hc.x, hc.y); H2[5] = mk2(hc.z, hc.w);
        H2[6] = mk2(hd.x, hd.y); H2[7] = mk2(hd.z, hd.w);

        // dot_h: 2 packed chains of 4 + combine (short dep depth)
        f32x2 a2 = pk_mul(H2[0], tw2[0]);
        f32x2 b2 = pk_mul(H2[1], tw2[1]);
        a2 = pk_fma(H2[2], tw2[2], a2);
        b2 = pk_fma(H2[3], tw2[3], b2);
        a2 = pk_fma(H2[4], tw2[4], a2);
        b2 = pk_fma(H2[5], tw2[5], b2);
        a2 = pk_fma(H2[6], tw2[6], a2);
        b2 = pk_fma(H2[7], tw2[7], b2);
        f32x2 c2 = pk_add(a2, b2);
        float dh = c2.x + c2.y;
        dh = row16_sum(dh);

        const float e = __expf(2.0f * (dxb + dh));
        const float h = (1.0f - 2.0f * __builtin_amdgcn_rcpf(e + 1.0f)) * invn;
        hl = h;

        // publish ASAP (relaxed agent store, no fence)
        if (i == 0) {
            __hip_atomic_store(slots + ((size_t)(par ^ 1) * BB + b) * HH + r,
                               ((u64)(unsigned)(s + 1) << 32) | (unsigned)__float_as_uint(h),
                               __ATOMIC_RELAXED, __HIP_MEMORY_SCOPE_AGENT);
        }

        // x(s+1) prefetch: in flight under Phase U, consumed at next loop top
        if (s + 1 < TT) {
            const float4* xn = reinterpret_cast<const float4*>(x + ((size_t)b * TT + (s + 1)) * II);
            px0 = xn[i]; px1 = xn[16 + i]; px2 = xn[32 + i]; px3 = xn[48 + i];
        }

        // ---- Phase U: F += (gamma*input)*h (gamma from AGPR) ----
        const f32x2 h2v = mk2(h, h);
#pragma unroll
        for (int j = 0; j < 8; ++j)
            F2[j] = pk_fma(pk_mul(X2[j], ag_read2(Ga[2*j], Ga[2*j+1])), h2v, F2[j]);
#pragma unroll
        for (int j = 0; j < 8; ++j)
            F2[8 + j] = pk_fma(pk_mul(ag_read2(Ga[16 + 2*j], Ga[16 + 2*j+1]), H2[j]), h2v, F2[8 + j]);
    }

    // ---- epilogue: F_T, h_T ----
    {
        float4* fo = reinterpret_cast<float4*>(out + 12288 + ((size_t)b * HH + r) * FWID);
#pragma unroll
        for (int k = 0; k < 8; ++k) {
            float4 v;
            v.x = F2[2*k].x; v.y = F2[2*k].y; v.z = F2[2*k+1].x; v.w = F2[2*k+1].y;
            fo[k * 16 + i] = v;
        }
    }
    if (i == 0) out[4096 + (size_t)b * HH + r] = hl;

    // tag_space: sl==0 blocks (one per batch) gather final h (stamp TT, parity 0)
    if (sl == 0) {
        if (wv == 0) {
            gather_to_lds(slots + ((size_t)(TT & 1) * BB + b) * HH, lane,
                          (unsigned)TT, lh[0], &lflag[0], TT + 1);
        }
        while (__hip_atomic_load(&lflag[0], __ATOMIC_ACQUIRE, __HIP_MEMORY_SCOPE_WORKGROUP) <= TT) {
            __builtin_amdgcn_s_sleep(1);
        }
        if (tid < OO) {
            const float* hv = lh[0];
            float acc = bout[tid];
            const float* wo = wout + (size_t)tid * HH;
#pragma unroll 4
            for (int jj = 0; jj < HH; ++jj) acc = fmaf(wo[jj], hv[jj], acc);
            out[(size_t)b * OO + tid] = acc;
        }
    }
}

extern "C" void kernel_launch(void* const* d_in, const int* in_sizes, int n_in,
                              void* d_out, int out_size, void* d_ws, size_t ws_size,
                              hipStream_t stream) {
    (void)in_sizes; (void)n_in; (void)out_size; (void)ws_size;
    const float* x    = (const float*)d_in[0];
    const float* wlam = (const float*)d_in[1];
    const float* wgam = (const float*)d_in[2];
    const float* w    = (const float*)d_in[3];
    const float* bias = (const float*)d_in[4];
    const float* wout = (const float*)d_in[5];
    const float* bout = (const float*)d_in[6];
    float* out = (float*)d_out;

    u64* slots = (u64*)d_ws;

    // stamp 0 + h = 0.0 is exactly what step 0 consumes
    hipMemsetAsync(d_ws, 0, 2ull * BB * HH * 8ull, stream);

    // Plain launch: grid 256 <= co-residency capacity (launch_bounds(512,2));
    // no grid-wide sync primitive is used (R14: coop replay cost ~40-75us).
    hipLaunchKernelGGL(stpn_kernel, dim3(256), dim3(512), 0, stream,
                       x, wlam, wgam, w, bias, wout, bout, out, slots);
}

// Round 12
// 241.987 us; speedup vs baseline: 1.0443x; 1.0443x over previous
//
#include <hip/hip_runtime.h>

#define BB 32
#define TT 128
#define II 256
#define HH 256
#define OO 128
#define FWID 512  // H + I

// d_ws: u64 slots[2][BB][HH] (parity, batch, row) = 128 KB.
// Slot = (stamp<<32)|float_bits(h); step s consumes stamp>=s from parity s&1,
// publishes stamp s+1 into parity (s+1)&1. Agent-scope relaxed (no fences);
// protocol proven on HW. Overwrite safety: publish(s+1) only after this
// block's gather(s) => all stamp-(s-1) readers retired. u64 cannot tear.
//
// R24 = exact revert to R10/R22 (best measured: kernel 173-183us, harness
// 220.7) + one on-chain micro: __expf -> __builtin_amdgcn_exp2f (drops the
// libm range-fixup around v_exp_f32; ~20-40cy on the publish-critical path;
// y->+inf => h->+invn, y->-inf => h->-invn, both correct limits).
//  - R23 AGPR stash REVERTED: 96 asm-volatile ag_reads serialized the VALU
//    (+55us). Its null-information: weight re-streaming was NEVER on the
//    critical path (hidden under relay wait). Single-floor model confirmed:
//    the h-relay chain (publish -> MALL visibility -> poll discovery) is the
//    binding constraint at ~3300cy/step; compute + weight streams hide under.
//  - All relay micro-levers and 3 structural redesigns measured null/negative
//    across R14-R23; if this round is flat, the kernel is at the inter-XCD
//    communication latency floor (128 sequential MALL broadcast rounds).

typedef unsigned long long u64;
typedef float f32x2 __attribute__((ext_vector_type(2)));

__device__ __forceinline__ f32x2 mk2(float a, float b) { f32x2 r; r.x = a; r.y = b; return r; }

__device__ __forceinline__ f32x2 pk_fma(f32x2 a, f32x2 b, f32x2 c) {
    f32x2 d;
    asm("v_pk_fma_f32 %0, %1, %2, %3" : "=v"(d) : "v"(a), "v"(b), "v"(c));
    return d;
}
__device__ __forceinline__ f32x2 pk_mul(f32x2 a, f32x2 b) {
    f32x2 d;
    asm("v_pk_mul_f32 %0, %1, %2" : "=v"(d) : "v"(a), "v"(b));
    return d;
}
__device__ __forceinline__ f32x2 pk_add(f32x2 a, f32x2 b) {
    f32x2 d;
    asm("v_pk_add_f32 %0, %1, %2" : "=v"(d) : "v"(a), "v"(b));
    return d;
}

template<int CTRL>
__device__ __forceinline__ float dpp_add(float x) {
    int t = __builtin_amdgcn_update_dpp(0, __float_as_int(x), CTRL, 0xF, 0xF, true);
    return x + __int_as_float(t);
}
// 16-lane butterfly sum via DPP row_ror; result valid in all 16 lanes.
__device__ __forceinline__ float row16_sum(float x) {
    x = dpp_add<0x128>(x);  // row_ror:8
    x = dpp_add<0x124>(x);  // row_ror:4
    x = dpp_add<0x122>(x);  // row_ror:2
    x = dpp_add<0x121>(x);  // row_ror:1
    return x;
}
// Paired version: interleaves the two dep chains (half the serial latency).
__device__ __forceinline__ void row16_sum2(float& a, float& b) {
    a = dpp_add<0x128>(a); b = dpp_add<0x128>(b);
    a = dpp_add<0x124>(a); b = dpp_add<0x124>(b);
    a = dpp_add<0x122>(a); b = dpp_add<0x122>(b);
    a = dpp_add<0x121>(a); b = dpp_add<0x121>(b);
}

__device__ __forceinline__ u64 slot_ld(const u64* p) {
    return __hip_atomic_load(p, __ATOMIC_RELAXED, __HIP_MEMORY_SCOPE_AGENT);
}

// One wave gathers 256 rows of one batch (4 slots/lane), stages h to LDS
// (ds_write_b128), release-stores an LDS flag. Depth-2 pipelined poll
// (R18-proven variant).
__device__ __forceinline__ void gather_to_lds(const u64* base, int lane, unsigned us,
                                              float* dst, int* flag, int fval) {
    const u64* p = base + 4 * lane;
    u64 a, b, c, d;
    {
        u64 a0 = slot_ld(p), b0 = slot_ld(p + 1), c0 = slot_ld(p + 2), d0 = slot_ld(p + 3);
        for (;;) {
            u64 a1 = slot_ld(p), b1 = slot_ld(p + 1), c1 = slot_ld(p + 2), d1 = slot_ld(p + 3);
            bool ok0 = ((unsigned)(a0 >> 32) >= us) & ((unsigned)(b0 >> 32) >= us) &
                       ((unsigned)(c0 >> 32) >= us) & ((unsigned)(d0 >> 32) >= us);
            if (__all(ok0)) { a = a0; b = b0; c = c0; d = d0; break; }
            a0 = slot_ld(p); b0 = slot_ld(p + 1); c0 = slot_ld(p + 2); d0 = slot_ld(p + 3);
            bool ok1 = ((unsigned)(a1 >> 32) >= us) & ((unsigned)(b1 >> 32) >= us) &
                       ((unsigned)(c1 >> 32) >= us) & ((unsigned)(d1 >> 32) >= us);
            if (__all(ok1)) { a = a1; b = b1; c = c1; d = d1; break; }
        }
    }
    float4 hv;
    hv.x = __uint_as_float((unsigned)a);
    hv.y = __uint_as_float((unsigned)b);
    hv.z = __uint_as_float((unsigned)c);
    hv.w = __uint_as_float((unsigned)d);
    *reinterpret_cast<float4*>(dst + 4 * lane) = hv;
    if (lane == 0)  // release drains the wave's ds_write before the flag
        __hip_atomic_store(flag, fval, __ATOMIC_RELEASE, __HIP_MEMORY_SCOPE_WORKGROUP);
}

__global__ __launch_bounds__(512, 2) __attribute__((amdgpu_waves_per_eu(2, 2)))
void stpn_kernel(const float* __restrict__ x,      // (B,T,I)
                 const float* __restrict__ wlam,   // (H,FWID)
                 const float* __restrict__ wgam,   // (H,FWID)
                 const float* __restrict__ w,      // (H,FWID)
                 const float* __restrict__ bias,   // (H)
                 const float* __restrict__ wout,   // (O,H)
                 const float* __restrict__ bout,   // (O)
                 float* __restrict__ out,          // tag(4096) | h_T(8192) | F_T
                 u64* __restrict__ slots)
{
    __shared__ __align__(16) float lh[2][HH];      // [parity][row]
    __shared__ int lflag[2];                       // [parity]

    const int tid  = threadIdx.x;
    const int bk   = blockIdx.x;
    const int b    = bk & 31;        // batch
    const int sl   = bk >> 5;        // row slice 0..7 (32 rows each)
    const int wv   = tid >> 6;       // 0..7
    const int lane = tid & 63;
    const int g    = tid >> 4;       // 16-lane group 0..31 == row-within-slice
    const int i    = tid & 15;       // lane within group
    const int r    = sl * 32 + (g & 31);

    if (tid < 2) lflag[tid] = 0;

    // Per-lane f-chunks of row r: f = 64*k + 4*i + c, pair j = 2k+p covers c=2p,2p+1
    // (k<4 x-part, k>=4 h-part)
    f32x2 W2[16], Lm2[16], G2[16], F2[16];
    {
        const float4* wr = reinterpret_cast<const float4*>(w    + (size_t)r * FWID);
        const float4* lr = reinterpret_cast<const float4*>(wlam + (size_t)r * FWID);
        const float4* gr = reinterpret_cast<const float4*>(wgam + (size_t)r * FWID);
#pragma unroll
        for (int k = 0; k < 8; ++k) {
            float4 t;
            t = wr[k * 16 + i]; W2[2*k]  = mk2(t.x, t.y); W2[2*k+1]  = mk2(t.z, t.w);
            t = lr[k * 16 + i]; Lm2[2*k] = mk2(t.x, t.y); Lm2[2*k+1] = mk2(t.z, t.w);
            t = gr[k * 16 + i]; G2[2*k]  = mk2(t.x, t.y); G2[2*k+1]  = mk2(t.z, t.w);
            F2[2*k] = mk2(0.f, 0.f); F2[2*k+1] = mk2(0.f, 0.f);
        }
    }
    // OPACITY BARRIER (R10-measured best): values become unknown -> remat
    // from memory impossible; helps the scheduler keep them resident.
#pragma unroll
    for (int j = 0; j < 16; ++j) {
        asm volatile("" : "+v"(W2[j]));
        asm volatile("" : "+v"(Lm2[j]));
        asm volatile("" : "+v"(G2[j]));
    }
    const float bj = bias[r];
    float hl = 0.f;

    // preload x(0)
    float4 px0, px1, px2, px3;
    {
        const float4* xb4 = reinterpret_cast<const float4*>(x + (size_t)b * TT * II);
        px0 = xb4[i]; px1 = xb4[16 + i]; px2 = xb4[32 + i]; px3 = xb4[48 + i];
    }

    __syncthreads();   // lflag init visible

    for (int s = 0; s < TT; ++s) {
        const int par = s & 1;

        f32x2 X2[8];
        X2[0] = mk2(px0.x, px0.y); X2[1] = mk2(px0.z, px0.w);
        X2[2] = mk2(px1.x, px1.y); X2[3] = mk2(px1.z, px1.w);
        X2[4] = mk2(px2.x, px2.y); X2[5] = mk2(px2.z, px2.w);
        X2[6] = mk2(px3.x, px3.y); X2[7] = mk2(px3.z, px3.w);

        // ---- Phase P: independent of h(s), runs before the gather ----
        f32x2 tw2[8];                                  // h-part tw, kept for dot_h
        f32x2 dx2 = mk2(0.f, 0.f), nv2 = mk2(0.f, 0.f);
#pragma unroll
        for (int j = 0; j < 8; ++j) {                  // x-part pairs
            f32x2 t = pk_add(W2[j], F2[j]);
            dx2 = pk_fma(X2[j], t, dx2);
            nv2 = pk_fma(t, t, nv2);
        }
#pragma unroll
        for (int j = 0; j < 8; ++j) {                  // h-part pairs
            tw2[j] = pk_add(W2[8 + j], F2[8 + j]);
            nv2 = pk_fma(tw2[j], tw2[j], nv2);
        }
        float dxs = dx2.x + dx2.y;
        float nrm = nv2.x + nv2.y;
        row16_sum2(dxs, nrm);
        const float invn = __builtin_amdgcn_rsqf(nrm);   // eps 1e-16 negligible, nrm = O(1)
        const f32x2 invn2 = mk2(invn, invn);
        const float dxb = dxs + bj;

        // F decay (h-independent)
#pragma unroll
        for (int j = 0; j < 16; ++j) F2[j] = pk_mul(Lm2[j], pk_mul(F2[j], invn2));

        // ---- gather (wave 0, pipelined after Phase P; prio-boosted) ----
        if (wv == 0) {
            __builtin_amdgcn_s_setprio(1);
            gather_to_lds(slots + ((size_t)par * BB + b) * HH, lane,
                          (unsigned)s, lh[par], &lflag[par], s + 1);
            __builtin_amdgcn_s_setprio(0);
        }

        // ---- Phase W: LDS flag spin (sleep frees SIMD issue), consume h ----
        while (__hip_atomic_load(&lflag[par], __ATOMIC_ACQUIRE, __HIP_MEMORY_SCOPE_WORKGROUP) <= s) {
            __builtin_amdgcn_s_sleep(1);
        }
        const float4* lh4 = reinterpret_cast<const float4*>(lh[par]);
        float4 ha = lh4[i], hb = lh4[16 + i], hc = lh4[32 + i], hd = lh4[48 + i];
        f32x2 H2[8];
        H2[0] = mk2(ha.x, ha.y); H2[1] = mk2(ha.z, ha.w);
        H2[2] = mk2(hb.x, hb.y); H2[3] = mk2(hb.z, hb.w);
        H2[4] = mk2(hc.x, hc.y); H2[5] = mk2(hc.z, hc.w);
        H2[6] = mk2(hd.x, hd.y); H2[7] = mk2(hd.z, hd.w);

        // dot_h: 2 packed chains of 4 + combine (short dep depth)
        f32x2 a2 = pk_mul(H2[0], tw2[0]);
        f32x2 b2 = pk_mul(H2[1], tw2[1]);
        a2 = pk_fma(H2[2], tw2[2], a2);
        b2 = pk_fma(H2[3], tw2[3], b2);
        a2 = pk_fma(H2[4], tw2[4], a2);
        b2 = pk_fma(H2[5], tw2[5], b2);
        a2 = pk_fma(H2[6], tw2[6], a2);
        b2 = pk_fma(H2[7], tw2[7], b2);
        f32x2 c2 = pk_add(a2, b2);
        float dh = c2.x + c2.y;
        dh = row16_sum(dh);

        // tanh via raw v_exp_f32 (base-2): e = 2^(2*log2(e)*y). Limits:
        // y->+inf => e=inf => rcp=0 => h=+invn; y->-inf => e=0 => h=-invn. Both correct.
        const float e = __builtin_amdgcn_exp2f(2.885390082f * (dxb + dh));
        const float h = (1.0f - 2.0f * __builtin_amdgcn_rcpf(e + 1.0f)) * invn;
        hl = h;

        // publish ASAP (relaxed agent store, no fence)
        if (i == 0) {
            __hip_atomic_store(slots + ((size_t)(par ^ 1) * BB + b) * HH + r,
                               ((u64)(unsigned)(s + 1) << 32) | (unsigned)__float_as_uint(h),
                               __ATOMIC_RELAXED, __HIP_MEMORY_SCOPE_AGENT);
        }

        // x(s+1) prefetch: in flight under Phase U, consumed at next loop top
        if (s + 1 < TT) {
            const float4* xn = reinterpret_cast<const float4*>(x + ((size_t)b * TT + (s + 1)) * II);
            px0 = xn[i]; px1 = xn[16 + i]; px2 = xn[32 + i]; px3 = xn[48 + i];
        }

        // ---- Phase U: F += (gamma*input)*h ----
        const f32x2 h2v = mk2(h, h);
#pragma unroll
        for (int j = 0; j < 8; ++j)
            F2[j] = pk_fma(pk_mul(X2[j], G2[j]), h2v, F2[j]);
#pragma unroll
        for (int j = 0; j < 8; ++j)
            F2[8 + j] = pk_fma(pk_mul(G2[8 + j], H2[j]), h2v, F2[8 + j]);
    }

    // ---- epilogue: F_T, h_T ----
    {
        float4* fo = reinterpret_cast<float4*>(out + 12288 + ((size_t)b * HH + r) * FWID);
#pragma unroll
        for (int k = 0; k < 8; ++k) {
            float4 v;
            v.x = F2[2*k].x; v.y = F2[2*k].y; v.z = F2[2*k+1].x; v.w = F2[2*k+1].y;
            fo[k * 16 + i] = v;
        }
    }
    if (i == 0) out[4096 + (size_t)b * HH + r] = hl;

    // tag_space: sl==0 blocks (one per batch) gather final h (stamp TT, parity 0)
    if (sl == 0) {
        if (wv == 0) {
            gather_to_lds(slots + ((size_t)(TT & 1) * BB + b) * HH, lane,
                          (unsigned)TT, lh[0], &lflag[0], TT + 1);
        }
        while (__hip_atomic_load(&lflag[0], __ATOMIC_ACQUIRE, __HIP_MEMORY_SCOPE_WORKGROUP) <= TT) {
            __builtin_amdgcn_s_sleep(1);
        }
        if (tid < OO) {
            const float* hv = lh[0];
            float acc = bout[tid];
            const float* wo = wout + (size_t)tid * HH;
#pragma unroll 4
            for (int jj = 0; jj < HH; ++jj) acc = fmaf(wo[jj], hv[jj], acc);
            out[(size_t)b * OO + tid] = acc;
        }
    }
}

extern "C" void kernel_launch(void* const* d_in, const int* in_sizes, int n_in,
                              void* d_out, int out_size, void* d_ws, size_t ws_size,
                              hipStream_t stream) {
    (void)in_sizes; (void)n_in; (void)out_size; (void)ws_size;
    const float* x    = (const float*)d_in[0];
    const float* wlam = (const float*)d_in[1];
    const float* wgam = (const float*)d_in[2];
    const float* w    = (const float*)d_in[3];
    const float* bias = (const float*)d_in[4];
    const float* wout = (const float*)d_in[5];
    const float* bout = (const float*)d_in[6];
    float* out = (float*)d_out;

    u64* slots = (u64*)d_ws;

    // stamp 0 + h = 0.0 is exactly what step 0 consumes
    hipMemsetAsync(d_ws, 0, 2ull * BB * HH * 8ull, stream);

    // Plain launch: grid 256 <= co-residency capacity (launch_bounds(512,2));
    // no grid-wide sync primitive is used (R14: coop replay cost ~40-75us).
    hipLaunchKernelGGL(stpn_kernel, dim3(256), dim3(512), 0, stream,
                       x, wlam, wgam, w, bias, wout, bout, out, slots);
}

// Round 15
// 221.753 us; speedup vs baseline: 1.1396x; 1.0912x over previous
//
#include <hip/hip_runtime.h>

#define BB 32
#define TT 128
#define II 256
#define HH 256
#define OO 128
#define FWID 512  // H + I

// d_ws: u64 slots[2][BB][HH] (parity, batch, row) = 128 KB.
// Slot = (stamp<<32)|float_bits(h); step s consumes stamp>=s from parity s&1,
// publishes stamp s+1 into parity (s+1)&1. Agent-scope relaxed (no fences);
// protocol proven on HW. Overwrite safety: publish(s+1) only after this
// block's gather(s) => all stamp-(s-1) readers retired. u64 cannot tear.
//
// R27 = exact revert to R24 (proven best: kernel 173-184us, harness 220.7
// best sample). R25/R26 staggered-poll EXPERIMENT CLOSED after two
// correctness failures: inline-asm loads are invisible to the compiler's
// hazard tracker, and register-allocator live-range splitting reuses the
// physical registers of in-flight writebacks (R26: h-magnitude values
// scattered into F_T). The safe implementation of the same cadence idea
// (compiler-visible depth-2, R18) already measured null.
// Session ledger: every relay lever (poll concurrency/cadence/path, sc0/sc1
// L2 fast-path x3, dual-batch, LDS weights, occupancy/opacity/AGPR residency)
// is measured null, negative, or unsound. Remaining period = 128 sequential
// cross-XCD MALL broadcast rounds ~1.35us each: a latency floor, not a
// memory/compute roofline (VALU 46%, HBM 2.7%, LDS-conflict 0).

typedef unsigned long long u64;
typedef float f32x2 __attribute__((ext_vector_type(2)));

__device__ __forceinline__ f32x2 mk2(float a, float b) { f32x2 r; r.x = a; r.y = b; return r; }

__device__ __forceinline__ f32x2 pk_fma(f32x2 a, f32x2 b, f32x2 c) {
    f32x2 d;
    asm("v_pk_fma_f32 %0, %1, %2, %3" : "=v"(d) : "v"(a), "v"(b), "v"(c));
    return d;
}
__device__ __forceinline__ f32x2 pk_mul(f32x2 a, f32x2 b) {
    f32x2 d;
    asm("v_pk_mul_f32 %0, %1, %2" : "=v"(d) : "v"(a), "v"(b));
    return d;
}
__device__ __forceinline__ f32x2 pk_add(f32x2 a, f32x2 b) {
    f32x2 d;
    asm("v_pk_add_f32 %0, %1, %2" : "=v"(d) : "v"(a), "v"(b));
    return d;
}

template<int CTRL>
__device__ __forceinline__ float dpp_add(float x) {
    int t = __builtin_amdgcn_update_dpp(0, __float_as_int(x), CTRL, 0xF, 0xF, true);
    return x + __int_as_float(t);
}
// 16-lane butterfly sum via DPP row_ror; result valid in all 16 lanes.
__device__ __forceinline__ float row16_sum(float x) {
    x = dpp_add<0x128>(x);  // row_ror:8
    x = dpp_add<0x124>(x);  // row_ror:4
    x = dpp_add<0x122>(x);  // row_ror:2
    x = dpp_add<0x121>(x);  // row_ror:1
    return x;
}
// Paired version: interleaves the two dep chains (half the serial latency).
__device__ __forceinline__ void row16_sum2(float& a, float& b) {
    a = dpp_add<0x128>(a); b = dpp_add<0x128>(b);
    a = dpp_add<0x124>(a); b = dpp_add<0x124>(b);
    a = dpp_add<0x122>(a); b = dpp_add<0x122>(b);
    a = dpp_add<0x121>(a); b = dpp_add<0x121>(b);
}

__device__ __forceinline__ u64 slot_ld(const u64* p) {
    return __hip_atomic_load(p, __ATOMIC_RELAXED, __HIP_MEMORY_SCOPE_AGENT);
}

// One wave gathers 256 rows of one batch (4 slots/lane), stages h to LDS
// (ds_write_b128), release-stores an LDS flag. Depth-2 pipelined poll
// (R18-proven variant; compiler-visible loads -> writeback-safe).
__device__ __forceinline__ void gather_to_lds(const u64* base, int lane, unsigned us,
                                              float* dst, int* flag, int fval) {
    const u64* p = base + 4 * lane;
    u64 a, b, c, d;
    {
        u64 a0 = slot_ld(p), b0 = slot_ld(p + 1), c0 = slot_ld(p + 2), d0 = slot_ld(p + 3);
        for (;;) {
            u64 a1 = slot_ld(p), b1 = slot_ld(p + 1), c1 = slot_ld(p + 2), d1 = slot_ld(p + 3);
            bool ok0 = ((unsigned)(a0 >> 32) >= us) & ((unsigned)(b0 >> 32) >= us) &
                       ((unsigned)(c0 >> 32) >= us) & ((unsigned)(d0 >> 32) >= us);
            if (__all(ok0)) { a = a0; b = b0; c = c0; d = d0; break; }
            a0 = slot_ld(p); b0 = slot_ld(p + 1); c0 = slot_ld(p + 2); d0 = slot_ld(p + 3);
            bool ok1 = ((unsigned)(a1 >> 32) >= us) & ((unsigned)(b1 >> 32) >= us) &
                       ((unsigned)(c1 >> 32) >= us) & ((unsigned)(d1 >> 32) >= us);
            if (__all(ok1)) { a = a1; b = b1; c = c1; d = d1; break; }
        }
    }
    float4 hv;
    hv.x = __uint_as_float((unsigned)a);
    hv.y = __uint_as_float((unsigned)b);
    hv.z = __uint_as_float((unsigned)c);
    hv.w = __uint_as_float((unsigned)d);
    *reinterpret_cast<float4*>(dst + 4 * lane) = hv;
    if (lane == 0)  // release drains the wave's ds_write before the flag
        __hip_atomic_store(flag, fval, __ATOMIC_RELEASE, __HIP_MEMORY_SCOPE_WORKGROUP);
}

__global__ __launch_bounds__(512, 2) __attribute__((amdgpu_waves_per_eu(2, 2)))
void stpn_kernel(const float* __restrict__ x,      // (B,T,I)
                 const float* __restrict__ wlam,   // (H,FWID)
                 const float* __restrict__ wgam,   // (H,FWID)
                 const float* __restrict__ w,      // (H,FWID)
                 const float* __restrict__ bias,   // (H)
                 const float* __restrict__ wout,   // (O,H)
                 const float* __restrict__ bout,   // (O)
                 float* __restrict__ out,          // tag(4096) | h_T(8192) | F_T
                 u64* __restrict__ slots)
{
    __shared__ __align__(16) float lh[2][HH];      // [parity][row]
    __shared__ int lflag[2];                       // [parity]

    const int tid  = threadIdx.x;
    const int bk   = blockIdx.x;
    const int b    = bk & 31;        // batch
    const int sl   = bk >> 5;        // row slice 0..7 (32 rows each)
    const int wv   = tid >> 6;       // 0..7
    const int lane = tid & 63;
    const int g    = tid >> 4;       // 16-lane group 0..31 == row-within-slice
    const int i    = tid & 15;       // lane within group
    const int r    = sl * 32 + (g & 31);

    if (tid < 2) lflag[tid] = 0;

    // Per-lane f-chunks of row r: f = 64*k + 4*i + c, pair j = 2k+p covers c=2p,2p+1
    // (k<4 x-part, k>=4 h-part)
    f32x2 W2[16], Lm2[16], G2[16], F2[16];
    {
        const float4* wr = reinterpret_cast<const float4*>(w    + (size_t)r * FWID);
        const float4* lr = reinterpret_cast<const float4*>(wlam + (size_t)r * FWID);
        const float4* gr = reinterpret_cast<const float4*>(wgam + (size_t)r * FWID);
#pragma unroll
        for (int k = 0; k < 8; ++k) {
            float4 t;
            t = wr[k * 16 + i]; W2[2*k]  = mk2(t.x, t.y); W2[2*k+1]  = mk2(t.z, t.w);
            t = lr[k * 16 + i]; Lm2[2*k] = mk2(t.x, t.y); Lm2[2*k+1] = mk2(t.z, t.w);
            t = gr[k * 16 + i]; G2[2*k]  = mk2(t.x, t.y); G2[2*k+1]  = mk2(t.z, t.w);
            F2[2*k] = mk2(0.f, 0.f); F2[2*k+1] = mk2(0.f, 0.f);
        }
    }
    // OPACITY BARRIER (R10-measured best): values become unknown -> remat
    // from memory impossible; helps the scheduler keep them resident.
#pragma unroll
    for (int j = 0; j < 16; ++j) {
        asm volatile("" : "+v"(W2[j]));
        asm volatile("" : "+v"(Lm2[j]));
        asm volatile("" : "+v"(G2[j]));
    }
    const float bj = bias[r];
    float hl = 0.f;

    // preload x(0)
    float4 px0, px1, px2, px3;
    {
        const float4* xb4 = reinterpret_cast<const float4*>(x + (size_t)b * TT * II);
        px0 = xb4[i]; px1 = xb4[16 + i]; px2 = xb4[32 + i]; px3 = xb4[48 + i];
    }

    __syncthreads();   // lflag init visible

    for (int s = 0; s < TT; ++s) {
        const int par = s & 1;

        f32x2 X2[8];
        X2[0] = mk2(px0.x, px0.y); X2[1] = mk2(px0.z, px0.w);
        X2[2] = mk2(px1.x, px1.y); X2[3] = mk2(px1.z, px1.w);
        X2[4] = mk2(px2.x, px2.y); X2[5] = mk2(px2.z, px2.w);
        X2[6] = mk2(px3.x, px3.y); X2[7] = mk2(px3.z, px3.w);

        // ---- Phase P: independent of h(s), runs before the gather ----
        f32x2 tw2[8];                                  // h-part tw, kept for dot_h
        f32x2 dx2 = mk2(0.f, 0.f), nv2 = mk2(0.f, 0.f);
#pragma unroll
        for (int j = 0; j < 8; ++j) {                  // x-part pairs
            f32x2 t = pk_add(W2[j], F2[j]);
            dx2 = pk_fma(X2[j], t, dx2);
            nv2 = pk_fma(t, t, nv2);
        }
#pragma unroll
        for (int j = 0; j < 8; ++j) {                  // h-part pairs
            tw2[j] = pk_add(W2[8 + j], F2[8 + j]);
            nv2 = pk_fma(tw2[j], tw2[j], nv2);
        }
        float dxs = dx2.x + dx2.y;
        float nrm = nv2.x + nv2.y;
        row16_sum2(dxs, nrm);
        const float invn = __builtin_amdgcn_rsqf(nrm);   // eps 1e-16 negligible, nrm = O(1)
        const f32x2 invn2 = mk2(invn, invn);
        const float dxb = dxs + bj;

        // F decay (h-independent)
#pragma unroll
        for (int j = 0; j < 16; ++j) F2[j] = pk_mul(Lm2[j], pk_mul(F2[j], invn2));

        // ---- gather (wave 0, pipelined after Phase P; prio-boosted) ----
        if (wv == 0) {
            __builtin_amdgcn_s_setprio(1);
            gather_to_lds(slots + ((size_t)par * BB + b) * HH, lane,
                          (unsigned)s, lh[par], &lflag[par], s + 1);
            __builtin_amdgcn_s_setprio(0);
        }

        // ---- Phase W: LDS flag spin (sleep frees SIMD issue), consume h ----
        while (__hip_atomic_load(&lflag[par], __ATOMIC_ACQUIRE, __HIP_MEMORY_SCOPE_WORKGROUP) <= s) {
            __builtin_amdgcn_s_sleep(1);
        }
        const float4* lh4 = reinterpret_cast<const float4*>(lh[par]);
        float4 ha = lh4[i], hb = lh4[16 + i], hc = lh4[32 + i], hd = lh4[48 + i];
        f32x2 H2[8];
        H2[0] = mk2(ha.x, ha.y); H2[1] = mk2(ha.z, ha.w);
        H2[2] = mk2(hb.x, hb.y); H2[3] = mk2(hb.z, hb.w);
        H2[4] = mk2(hc.x, hc.y); H2[5] = mk2(hc.z, hc.w);
        H2[6] = mk2(hd.x, hd.y); H2[7] = mk2(hd.z, hd.w);

        // dot_h: 2 packed chains of 4 + combine (short dep depth)
        f32x2 a2 = pk_mul(H2[0], tw2[0]);
        f32x2 b2 = pk_mul(H2[1], tw2[1]);
        a2 = pk_fma(H2[2], tw2[2], a2);
        b2 = pk_fma(H2[3], tw2[3], b2);
        a2 = pk_fma(H2[4], tw2[4], a2);
        b2 = pk_fma(H2[5], tw2[5], b2);
        a2 = pk_fma(H2[6], tw2[6], a2);
        b2 = pk_fma(H2[7], tw2[7], b2);
        f32x2 c2 = pk_add(a2, b2);
        float dh = c2.x + c2.y;
        dh = row16_sum(dh);

        // tanh via raw v_exp_f32 (base-2): e = 2^(2*log2(e)*y). Limits:
        // y->+inf => e=inf => rcp=0 => h=+invn; y->-inf => e=0 => h=-invn. Both correct.
        const float e = __builtin_amdgcn_exp2f(2.885390082f * (dxb + dh));
        const float h = (1.0f - 2.0f * __builtin_amdgcn_rcpf(e + 1.0f)) * invn;
        hl = h;

        // publish ASAP (relaxed agent store, no fence)
        if (i == 0) {
            __hip_atomic_store(slots + ((size_t)(par ^ 1) * BB + b) * HH + r,
                               ((u64)(unsigned)(s + 1) << 32) | (unsigned)__float_as_uint(h),
                               __ATOMIC_RELAXED, __HIP_MEMORY_SCOPE_AGENT);
        }

        // x(s+1) prefetch: in flight under Phase U, consumed at next loop top
        if (s + 1 < TT) {
            const float4* xn = reinterpret_cast<const float4*>(x + ((size_t)b * TT + (s + 1)) * II);
            px0 = xn[i]; px1 = xn[16 + i]; px2 = xn[32 + i]; px3 = xn[48 + i];
        }

        // ---- Phase U: F += (gamma*input)*h ----
        const f32x2 h2v = mk2(h, h);
#pragma unroll
        for (int j = 0; j < 8; ++j)
            F2[j] = pk_fma(pk_mul(X2[j], G2[j]), h2v, F2[j]);
#pragma unroll
        for (int j = 0; j < 8; ++j)
            F2[8 + j] = pk_fma(pk_mul(G2[8 + j], H2[j]), h2v, F2[8 + j]);
    }

    // ---- epilogue: F_T, h_T ----
    {
        float4* fo = reinterpret_cast<float4*>(out + 12288 + ((size_t)b * HH + r) * FWID);
#pragma unroll
        for (int k = 0; k < 8; ++k) {
            float4 v;
            v.x = F2[2*k].x; v.y = F2[2*k].y; v.z = F2[2*k+1].x; v.w = F2[2*k+1].y;
            fo[k * 16 + i] = v;
        }
    }
    if (i == 0) out[4096 + (size_t)b * HH + r] = hl;

    // tag_space: sl==0 blocks (one per batch) gather final h (stamp TT, parity 0)
    if (sl == 0) {
        if (wv == 0) {
            gather_to_lds(slots + ((size_t)(TT & 1) * BB + b) * HH, lane,
                          (unsigned)TT, lh[0], &lflag[0], TT + 1);
        }
        while (__hip_atomic_load(&lflag[0], __ATOMIC_ACQUIRE, __HIP_MEMORY_SCOPE_WORKGROUP) <= TT) {
            __builtin_amdgcn_s_sleep(1);
        }
        if (tid < OO) {
            const float* hv = lh[0];
            float acc = bout[tid];
            const float* wo = wout + (size_t)tid * HH;
#pragma unroll 4
            for (int jj = 0; jj < HH; ++jj) acc = fmaf(wo[jj], hv[jj], acc);
            out[(size_t)b * OO + tid] = acc;
        }
    }
}

extern "C" void kernel_launch(void* const* d_in, const int* in_sizes, int n_in,
                              void* d_out, int out_size, void* d_ws, size_t ws_size,
                              hipStream_t stream) {
    (void)in_sizes; (void)n_in; (void)out_size; (void)ws_size;
    const float* x    = (const float*)d_in[0];
    const float* wlam = (const float*)d_in[1];
    const float* wgam = (const float*)d_in[2];
    const float* w    = (const float*)d_in[3];
    const float* bias = (const float*)d_in[4];
    const float* wout = (const float*)d_in[5];
    const float* bout = (const float*)d_in[6];
    float* out = (float*)d_out;

    u64* slots = (u64*)d_ws;

    // stamp 0 + h = 0.0 is exactly what step 0 consumes
    hipMemsetAsync(d_ws, 0, 2ull * BB * HH * 8ull, stream);

    // Plain launch: grid 256 <= co-residency capacity (launch_bounds(512,2));
    // no grid-wide sync primitive is used (R14: coop replay cost ~40-75us).
    hipLaunchKernelGGL(stpn_kernel, dim3(256), dim3(512), 0, stream,
                       x, wlam, wgam, w, bias, wout, bout, out, slots);
}